// Round 1
// baseline (371.651 us; speedup 1.0000x reference)
//
#include <hip/hip_runtime.h>
#include <math.h>

#define BB 4
#define CC 64
#define HH_ 128
#define WW 128
#define HPW (HH_*WW)     // 16384
#define KH 64
#define KW 64
#define KSZ 7
#define AA 16
#define EPSV 1e-5f

__device__ __forceinline__ float sigm(float x){ return 1.0f/(1.0f+expf(-x)); }

// ---------------- K1: per-(b,c) mean of x ----------------
__global__ void k_mean(const float* __restrict__ x, float* __restrict__ g){
  int bc = blockIdx.x; int t = threadIdx.x;
  const float4* p = (const float4*)(x + (size_t)bc*HPW);
  float s = 0.f;
  for(int i=t;i<HPW/4;i+=256){ float4 v = p[i]; s += v.x+v.y+v.z+v.w; }
  for(int o=32;o>0;o>>=1) s += __shfl_down(s,o);
  __shared__ float ls[4];
  if((t&63)==0) ls[t>>6]=s;
  __syncthreads();
  if(t==0) g[bc] = (ls[0]+ls[1]+ls[2]+ls[3]) * (1.0f/HPW);
}

// ---------------- K2: attention + weff + dsT (single block) ----------------
__global__ void k_att(const float* __restrict__ g, const float* __restrict__ w,
  const float* __restrict__ ratio_p,
  const float* __restrict__ o1fc, const float* __restrict__ o1g,const float* __restrict__ o1b,
  const float* __restrict__ o1m,const float* __restrict__ o1v,
  const float* __restrict__ o1cw,const float* __restrict__ o1cb,
  const float* __restrict__ o1fw,const float* __restrict__ o1fb,
  const float* __restrict__ o2fc, const float* __restrict__ o2g,const float* __restrict__ o2b,
  const float* __restrict__ o2m,const float* __restrict__ o2v,
  const float* __restrict__ o2cw,const float* __restrict__ o2cb,
  const float* __restrict__ o2fw,const float* __restrict__ o2fb,
  const float* __restrict__ spw,const float* __restrict__ spb,
  const float* __restrict__ dsw, float* __restrict__ weff, float* __restrict__ dsT)
{
  __shared__ float sg[BB][CC], sa1[BB][AA], sa2[BB][AA];
  __shared__ float sc1[BB][CC], sf1[BB][CC], sc2[BB][CC], sf2[BB][CC], ssp[BB][9];
  int t = threadIdx.x;
  sg[t>>6][t&63] = g[t];
  __syncthreads();
  if(t < BB*AA){
    int b=t/AA, j=t%AA;
    float v1=0.f, v2=0.f;
    for(int c=0;c<CC;c++){ float gv = sg[b][c]; v1 += gv*o1fc[j*CC+c]; v2 += gv*o2fc[j*CC+c]; }
    v1 = (v1-o1m[j])*rsqrtf(o1v[j]+EPSV)*o1g[j]+o1b[j]; sa1[b][j]=fmaxf(v1,0.f);
    v2 = (v2-o2m[j])*rsqrtf(o2v[j]+EPSV)*o2g[j]+o2b[j]; sa2[b][j]=fmaxf(v2,0.f);
  }
  __syncthreads();
  { int b=t>>6, c=t&63;
    float d1=o1cb[c], d2=o1fb[c], d3=o2cb[c], d4=o2fb[c];
    for(int j=0;j<AA;j++){
      float a1=sa1[b][j], a2=sa2[b][j];
      d1+=a1*o1cw[c*AA+j]; d2+=a1*o1fw[c*AA+j];
      d3+=a2*o2cw[c*AA+j]; d4+=a2*o2fw[c*AA+j];
    }
    sc1[b][c]=sigm(d1); sf1[b][c]=sigm(d2); sc2[b][c]=sigm(d3); sf2[b][c]=sigm(d4);
  }
  if(t < BB*9){ int b=t/9,k=t%9; float d=spb[k]; for(int j=0;j<AA;j++) d+=sa2[b][j]*spw[k*AA+j]; ssp[b][k]=sigm(d); }
  __syncthreads();
  {
    int b=t>>6, o=t&63;
    float S1=0.f; float M[9];
    for(int e=0;e<9;e++) M[e]=0.f;
    for(int i=0;i<CC;i++){
      const float* wp = w + ((size_t)(o*CC+i))*9;
      float w9[9]; float m=0.f;
      #pragma unroll
      for(int e=0;e<9;e++){ w9[e]=wp[e]; m+=w9[e]; }
      m *= (1.0f/9.0f);
      S1 += m * sc1[b][i];
      float c2v = sc2[b][i];
      #pragma unroll
      for(int e=0;e<9;e++) M[e] += (w9[e]-m)*c2v;
    }
    const float Dm[3][3] = {{2.f,2.f,2.f},{1.7320508075688772f,0.f,-1.7320508075688772f},{1.f,-2.f,1.f}};
    const float Di[3][3] = {{0.16666666666666666f,0.28867513459481287f,0.16666666666666666f},
                            {0.16666666666666666f,0.f,-0.3333333333333333f},
                            {0.16666666666666666f,-0.28867513459481287f,0.16666666666666666f}};
    float U[3][3], T[3][3], V[3][3], R[3][3];
    for(int k=0;k<3;k++)for(int n=0;n<3;n++) U[k][n]=Dm[k][0]*M[0*3+n]+Dm[k][1]*M[1*3+n]+Dm[k][2]*M[2*3+n];
    for(int k=0;k<3;k++)for(int l=0;l<3;l++) T[k][l]=(U[k][0]*Dm[l][0]+U[k][1]*Dm[l][1]+U[k][2]*Dm[l][2])*2.0f*ssp[b][k*3+l];
    for(int k=0;k<3;k++)for(int n=0;n<3;n++) V[k][n]=Di[k][0]*T[0][n]+Di[k][1]*T[1][n]+Di[k][2]*T[2][n];
    for(int k=0;k<3;k++)for(int l=0;l<3;l++) R[k][l]=V[k][0]*Di[l][0]+V[k][1]*Di[l][1]+V[k][2]*Di[l][2];
    float rr = ratio_p[0];
    float base = rr*4.0f*sf1[b][o]*S1;
    float w2f = (1.0f-rr)*4.0f*sf2[b][o];
    for(int e=0;e<9;e++) weff[(size_t)(b*CC+o)*9+e] = base + w2f*R[e/3][e%3];
  }
  // dsT[(ci*7+k)*64 + co] = ds_w[co, ci, k]
  for(int idx=t; idx<CC*CC*KSZ; idx+=256){
    int co = idx&63; int rest = idx>>6;
    dsT[idx] = dsw[(size_t)co*(CC*KSZ) + rest];
  }
}

// ---------------- K3a: HH from x ----------------
__global__ void k_dwt_hh(const float* __restrict__ x, float* __restrict__ HHb){
  int idx = blockIdx.x*256 + threadIdx.x;   // BB*CC*KH*KW = 1048576
  int w = idx & 63; int h = (idx>>6)&63; int bc = idx>>12;
  const float* xp = x + (size_t)bc*HPW;
  float2 r0 = *(const float2*)(xp + (2*h)*WW + 2*w);
  float2 r1 = *(const float2*)(xp + (2*h+1)*WW + 2*w);
  HHb[idx] = 0.5f*(r0.x - r1.x - r0.y + r1.y);
}

// ---------------- K3b: out = 2x + iwt(0,0,0, conv(HH)-HH), NCHW into d_out ----------------
__global__ void k_iwt(const float* __restrict__ HHb, const float* __restrict__ x,
                      const float* __restrict__ weff, float* __restrict__ outb){
  int bc = blockIdx.x;
  float wk[9];
  #pragma unroll
  for(int e=0;e<9;e++) wk[e] = weff[(size_t)bc*9+e];
  const float* Hp = HHb + (size_t)bc*KH*KW;
  const float* xp = x + (size_t)bc*HPW;
  float* op = outb + (size_t)bc*HPW;
  for(int idx=threadIdx.x; idx<KH*KW; idx+=256){
    int h = idx>>6, w = idx&63;
    float acc = 0.f;
    #pragma unroll
    for(int dh=-1;dh<=1;dh++){ int hh=h+dh; if(hh<0||hh>=KH) continue;
      #pragma unroll
      for(int dw=-1;dw<=1;dw++){ int ww=w+dw; if(ww<0||ww>=KW) continue;
        acc += wk[(dh+1)*3+(dw+1)] * Hp[hh*KW+ww]; } }
    float d = 0.5f*(acc - Hp[idx]);
    float2 xr0 = *(const float2*)(xp + (2*h)*WW + 2*w);
    float2 xr1 = *(const float2*)(xp + (2*h+1)*WW + 2*w);
    float2 o0, o1;
    o0.x = 2.f*xr0.x + d;  o0.y = 2.f*xr0.y - d;
    o1.x = 2.f*xr1.x - d;  o1.y = 2.f*xr1.y + d;
    *(float2*)(op + (2*h)*WW + 2*w) = o0;
    *(float2*)(op + (2*h+1)*WW + 2*w) = o1;
  }
}

// ---------------- K3c: transpose NCHW out -> outT[b,h,w,c] ----------------
__global__ void k_transpose(const float* __restrict__ outb, float* __restrict__ outT){
  int b = blockIdx.x >> 7; int h = blockIdx.x & 127;
  __shared__ float tile[CC][WW+1];
  int t = threadIdx.x;
  for(int e=t; e<CC*WW; e+=256){ int c=e>>7, w=e&127; tile[c][w] = outb[((size_t)(b*CC+c)*HH_+h)*WW + w]; }
  __syncthreads();
  float* dst = outT + ((size_t)(b*HH_+h))*WW*CC;
  for(int e=t; e<CC*WW; e+=256){ int w=e>>6, c=e&63; dst[e] = tile[c][w]; }
}

// ---------------- K4: offset conv (7 ch) + BN + tanh + cumsum -> dy ----------------
__global__ void k_off(const float* __restrict__ outT, const float* __restrict__ offw,
  const float* __restrict__ offb, const float* __restrict__ obg, const float* __restrict__ obb,
  const float* __restrict__ obm, const float* __restrict__ obv, float* __restrict__ dyb)
{
  __shared__ float sow[KSZ*CC*9];
  __shared__ float sscale[KSZ], sshift[KSZ], sob[KSZ];
  int t = threadIdx.x;
  for(int i=t;i<KSZ*CC*9;i+=256) sow[i]=offw[i];
  if(t<KSZ){ float sc = obg[t]*rsqrtf(obv[t]+EPSV); sscale[t]=sc; sshift[t]=obb[t]-obm[t]*sc; sob[t]=offb[t]; }
  __syncthreads();
  int pos = blockIdx.x*256 + t;
  int b = pos>>14; int rem = pos&16383; int h = rem>>7; int w = rem&127;
  float acc[KSZ];
  #pragma unroll
  for(int k=0;k<KSZ;k++) acc[k]=sob[k];
  for(int dh=-1;dh<=1;dh++){ int hh=h+dh; if(hh<0||hh>=HH_) continue;
    for(int dw=-1;dw<=1;dw++){ int ww=w+dw; if(ww<0||ww>=WW) continue;
      int tap=(dh+1)*3+(dw+1);
      const float4* p = (const float4*)(outT + ((size_t)(b*HH_+hh)*WW+ww)*CC);
      for(int c4=0;c4<16;c4++){ float4 v = p[c4];
        const float* wr0 = &sow[(c4*4)*9 + tap];
        #pragma unroll
        for(int k=0;k<KSZ;k++){
          const float* wrow = wr0 + k*576;
          acc[k] += v.x*wrow[0] + v.y*wrow[9] + v.z*wrow[18] + v.w*wrow[27];
        }
      }
    }
  }
  float y[KSZ];
  #pragma unroll
  for(int k=0;k<KSZ;k++) y[k] = tanhf(acc[k]*sscale[k]+sshift[k]);
  float d0 = y[0]+y[1]+y[2], d1=y[1]+y[2], d2=y[2];
  float d4=y[4], d5=y[4]+y[5], d6=y[4]+y[5]+y[6];
  size_t base = ((size_t)b*KSZ)*HPW + rem;
  dyb[base          ] = d0;
  dyb[base +   HPW  ] = d1;
  dyb[base + 2*HPW  ] = d2;
  dyb[base + 3*HPW  ] = 0.f;
  dyb[base + 4*HPW  ] = d4;
  dyb[base + 5*HPW  ] = d5;
  dyb[base + 6*HPW  ] = d6;
}

// ---------------- K5: deform sample + (7x1,stride 7) conv -> y (into d_out NCHW) ----------------
__global__ void k_dsconv(const float* __restrict__ outT, const float* __restrict__ dyb,
  const float* __restrict__ dsT, const float* __restrict__ dsb, float* __restrict__ yout)
{
  int wt = blockIdx.x; int h = blockIdx.y; int b = blockIdx.z;
  int w0 = wt*16;
  __shared__ float S[KSZ][16][65];
  __shared__ int sr0[KSZ][16], sr1[KSZ][16], scol[KSZ][16];
  __shared__ float swr[KSZ][16];
  int t = threadIdx.x;
  if(t < KSZ*16){
    int k=t>>4, j=t&15; int w=w0+j;
    float dv = dyb[((size_t)(b*KSZ+k)*HH_+h)*WW+w];
    float r = (float)h + dv;
    r = fminf(fmaxf(r,0.f),127.f);
    float rf = floorf(r);
    int r0 = (int)rf;
    float wr = r - rf;
    int r1 = min(r0+1,127);
    int c = w + k - 3; c = max(0,min(c,127));
    sr0[k][j]=r0; sr1[k][j]=r1; scol[k][j]=c; swr[k][j]=wr;
  }
  __syncthreads();
  for(int idx=t; idx<KSZ*16*64; idx+=256){
    int ci = idx&63; int j=(idx>>6)&15; int k=idx>>10;
    int r0=sr0[k][j], r1=sr1[k][j], c=scol[k][j]; float wr=swr[k][j];
    const float* p0 = outT + ((size_t)(b*HH_+r0)*WW+c)*CC;
    const float* p1 = outT + ((size_t)(b*HH_+r1)*WW+c)*CC;
    S[k][j][ci] = (1.f-wr)*p0[ci] + wr*p1[ci];
  }
  __syncthreads();
  int j = t&15; int co4 = t>>4;
  for(int rep=0;rep<4;rep++){
    int co = rep*16 + co4;
    float acc = dsb[co];
    for(int ci=0;ci<CC;ci++){
      const float* dw = dsT + (size_t)(ci*KSZ)*CC + co;
      #pragma unroll
      for(int k=0;k<KSZ;k++) acc += dw[(size_t)k*CC] * S[k][j][ci];
    }
    yout[((size_t)(b*CC+co)*HH_+h)*WW + (w0+j)] = acc;
  }
}

// ---------------- K6: GN partial stats per (b,c) ----------------
__global__ void k_gnstat(const float* __restrict__ y, float* __restrict__ stats){
  int bc = blockIdx.x; int t = threadIdx.x;
  const float4* p = (const float4*)(y + (size_t)bc*HPW);
  float s=0.f, q=0.f;
  for(int i=t;i<HPW/4;i+=256){ float4 v=p[i];
    s += v.x+v.y+v.z+v.w; q += v.x*v.x+v.y*v.y+v.z*v.z+v.w*v.w; }
  for(int o=32;o>0;o>>=1){ s += __shfl_down(s,o); q += __shfl_down(q,o); }
  __shared__ float ls[4], lq[4];
  if((t&63)==0){ ls[t>>6]=s; lq[t>>6]=q; }
  __syncthreads();
  if(t==0){ stats[bc*2] = ls[0]+ls[1]+ls[2]+ls[3]; stats[bc*2+1] = lq[0]+lq[1]+lq[2]+lq[3]; }
}

// ---------------- K6b: finalize group stats ----------------
__global__ void k_gnfin(const float* __restrict__ stats, float* __restrict__ gstat){
  int t = threadIdx.x;
  if(t < BB*16){
    int b=t>>4, gp=t&15;
    float s=0.f,q=0.f;
    for(int i=0;i<4;i++){ int bc = b*CC + gp*4 + i; s += stats[bc*2]; q += stats[bc*2+1]; }
    float inv = 1.0f/(4.0f*HPW);
    float mu = s*inv;
    float var = q*inv - mu*mu;
    gstat[t*2] = mu; gstat[t*2+1] = rsqrtf(var+EPSV);
  }
}

// ---------------- K7: apply GN + affine + relu in place ----------------
__global__ void k_gnapply(float* __restrict__ y, const float* __restrict__ gstat,
  const float* __restrict__ gg, const float* __restrict__ gb){
  int idx = blockIdx.x*256 + threadIdx.x;   // float4 index, n/4 = 1048576
  float4* p = (float4*)y;
  int bc = idx >> 12;
  int b = bc>>6, c = bc&63;
  int gi = b*16 + (c>>2);
  float mu = gstat[gi*2], rstd = gstat[gi*2+1];
  float sc = rstd*gg[c], sh = gb[c]-mu*sc;
  float4 v = p[idx];
  v.x = fmaxf(v.x*sc+sh, 0.f);
  v.y = fmaxf(v.y*sc+sh, 0.f);
  v.z = fmaxf(v.z*sc+sh, 0.f);
  v.w = fmaxf(v.w*sc+sh, 0.f);
  p[idx] = v;
}

extern "C" void kernel_launch(void* const* d_in, const int* in_sizes, int n_in,
                              void* d_out, int out_size, void* d_ws, size_t ws_size,
                              hipStream_t stream) {
  const float* x      = (const float*)d_in[0];
  const float* weight = (const float*)d_in[1];
  const float* ratio  = (const float*)d_in[2];
  const float* o1fc   = (const float*)d_in[3];
  const float* o1g    = (const float*)d_in[4];
  const float* o1b    = (const float*)d_in[5];
  const float* o1m    = (const float*)d_in[6];
  const float* o1v    = (const float*)d_in[7];
  const float* o1cw   = (const float*)d_in[8];
  const float* o1cb   = (const float*)d_in[9];
  const float* o1fw   = (const float*)d_in[10];
  const float* o1fb   = (const float*)d_in[11];
  const float* o2fc   = (const float*)d_in[12];
  const float* o2g    = (const float*)d_in[13];
  const float* o2b    = (const float*)d_in[14];
  const float* o2m    = (const float*)d_in[15];
  const float* o2v    = (const float*)d_in[16];
  const float* o2cw   = (const float*)d_in[17];
  const float* o2cb   = (const float*)d_in[18];
  const float* o2fw   = (const float*)d_in[19];
  const float* o2fb   = (const float*)d_in[20];
  const float* spw    = (const float*)d_in[21];
  const float* spb    = (const float*)d_in[22];
  const float* offw   = (const float*)d_in[23];
  const float* offb   = (const float*)d_in[24];
  const float* obg    = (const float*)d_in[25];
  const float* obb    = (const float*)d_in[26];
  const float* obm    = (const float*)d_in[27];
  const float* obv    = (const float*)d_in[28];
  const float* dsw    = (const float*)d_in[29];
  const float* dsb    = (const float*)d_in[30];
  const float* gng    = (const float*)d_in[31];
  const float* gnb    = (const float*)d_in[32];

  float* ws    = (float*)d_ws;
  float* outT  = ws;                 // 4194304
  float* HHb   = ws + 4194304;       // 1048576
  float* dyb   = ws + 5242880;       // 458752
  float* gbuf  = ws + 5701632;       // 256
  float* weff  = ws + 5701888;       // 2304
  float* dsT   = ws + 5704192;       // 28672
  float* stats = ws + 5732864;       // 512
  float* gstat = ws + 5733376;       // 128
  float* outb  = (float*)d_out;      // NCHW scratch: out -> y -> final

  k_mean<<<256,256,0,stream>>>(x, gbuf);
  k_dwt_hh<<<4096,256,0,stream>>>(x, HHb);
  k_att<<<1,256,0,stream>>>(gbuf, weight, ratio,
    o1fc,o1g,o1b,o1m,o1v,o1cw,o1cb,o1fw,o1fb,
    o2fc,o2g,o2b,o2m,o2v,o2cw,o2cb,o2fw,o2fb,
    spw,spb, dsw, weff, dsT);
  k_iwt<<<256,256,0,stream>>>(HHb, x, weff, outb);
  k_transpose<<<512,256,0,stream>>>(outb, outT);
  k_off<<<256,256,0,stream>>>(outT, offw, offb, obg, obb, obm, obv, dyb);
  k_dsconv<<<dim3(8,128,4),256,0,stream>>>(outT, dyb, dsT, dsb, outb);
  k_gnstat<<<256,256,0,stream>>>(outb, stats);
  k_gnfin<<<1,64,0,stream>>>(stats, gstat);
  k_gnapply<<<4096,256,0,stream>>>(outb, gstat, gng, gnb);
}

// Round 2
// 301.804 us; speedup vs baseline: 1.2314x; 1.2314x over previous
//
#include <hip/hip_runtime.h>
#include <math.h>

#define BB 4
#define CC 64
#define HH_ 128
#define WW 128
#define HPW (HH_*WW)     // 16384
#define KH 64
#define KW 64
#define KSZ 7
#define AA 16
#define EPSV 1e-5f

__device__ __forceinline__ float sigm(float x){ return 1.0f/(1.0f+expf(-x)); }

// ---------------- K1: per-(b,c) mean of x ----------------
__global__ void k_mean(const float* __restrict__ x, float* __restrict__ g){
  int bc = blockIdx.x; int t = threadIdx.x;
  const float4* p = (const float4*)(x + (size_t)bc*HPW);
  float s = 0.f;
  for(int i=t;i<HPW/4;i+=256){ float4 v = p[i]; s += v.x+v.y+v.z+v.w; }
  for(int o=32;o>0;o>>=1) s += __shfl_down(s,o);
  __shared__ float ls[4];
  if((t&63)==0) ls[t>>6]=s;
  __syncthreads();
  if(t==0) g[bc] = (ls[0]+ls[1]+ls[2]+ls[3]) * (1.0f/HPW);
}

// ---------------- K2: attention + weff + dsT + offT ----------------
__global__ void k_att(const float* __restrict__ g, const float* __restrict__ w,
  const float* __restrict__ ratio_p,
  const float* __restrict__ o1fc, const float* __restrict__ o1g,const float* __restrict__ o1b,
  const float* __restrict__ o1m,const float* __restrict__ o1v,
  const float* __restrict__ o1cw,const float* __restrict__ o1cb,
  const float* __restrict__ o1fw,const float* __restrict__ o1fb,
  const float* __restrict__ o2fc, const float* __restrict__ o2g,const float* __restrict__ o2b,
  const float* __restrict__ o2m,const float* __restrict__ o2v,
  const float* __restrict__ o2cw,const float* __restrict__ o2cb,
  const float* __restrict__ o2fw,const float* __restrict__ o2fb,
  const float* __restrict__ spw,const float* __restrict__ spb,
  const float* __restrict__ dsw, const float* __restrict__ offw,
  float* __restrict__ weff, float* __restrict__ dsT, float* __restrict__ offT)
{
  __shared__ float sg[BB][CC], sa1[BB][AA], sa2[BB][AA];
  __shared__ float sc1[BB][CC], sf1[BB][CC], sc2[BB][CC], sf2[BB][CC], ssp[BB][9];
  int t = threadIdx.x;
  sg[t>>6][t&63] = g[t];
  __syncthreads();
  if(t < BB*AA){
    int b=t/AA, j=t%AA;
    float v1=0.f, v2=0.f;
    for(int c=0;c<CC;c++){ float gv = sg[b][c]; v1 += gv*o1fc[j*CC+c]; v2 += gv*o2fc[j*CC+c]; }
    v1 = (v1-o1m[j])*rsqrtf(o1v[j]+EPSV)*o1g[j]+o1b[j]; sa1[b][j]=fmaxf(v1,0.f);
    v2 = (v2-o2m[j])*rsqrtf(o2v[j]+EPSV)*o2g[j]+o2b[j]; sa2[b][j]=fmaxf(v2,0.f);
  }
  __syncthreads();
  { int b=t>>6, c=t&63;
    float d1=o1cb[c], d2=o1fb[c], d3=o2cb[c], d4=o2fb[c];
    for(int j=0;j<AA;j++){
      float a1=sa1[b][j], a2=sa2[b][j];
      d1+=a1*o1cw[c*AA+j]; d2+=a1*o1fw[c*AA+j];
      d3+=a2*o2cw[c*AA+j]; d4+=a2*o2fw[c*AA+j];
    }
    sc1[b][c]=sigm(d1); sf1[b][c]=sigm(d2); sc2[b][c]=sigm(d3); sf2[b][c]=sigm(d4);
  }
  if(t < BB*9){ int b=t/9,k=t%9; float d=spb[k]; for(int j=0;j<AA;j++) d+=sa2[b][j]*spw[k*AA+j]; ssp[b][k]=sigm(d); }
  __syncthreads();
  {
    int b=t>>6, o=t&63;
    float S1=0.f; float M[9];
    for(int e=0;e<9;e++) M[e]=0.f;
    for(int i=0;i<CC;i++){
      const float* wp = w + ((size_t)(o*CC+i))*9;
      float w9[9]; float m=0.f;
      #pragma unroll
      for(int e=0;e<9;e++){ w9[e]=wp[e]; m+=w9[e]; }
      m *= (1.0f/9.0f);
      S1 += m * sc1[b][i];
      float c2v = sc2[b][i];
      #pragma unroll
      for(int e=0;e<9;e++) M[e] += (w9[e]-m)*c2v;
    }
    const float Dm[3][3] = {{2.f,2.f,2.f},{1.7320508075688772f,0.f,-1.7320508075688772f},{1.f,-2.f,1.f}};
    const float Di[3][3] = {{0.16666666666666666f,0.28867513459481287f,0.16666666666666666f},
                            {0.16666666666666666f,0.f,-0.3333333333333333f},
                            {0.16666666666666666f,-0.28867513459481287f,0.16666666666666666f}};
    float U[3][3], T[3][3], V[3][3], R[3][3];
    for(int k=0;k<3;k++)for(int n=0;n<3;n++) U[k][n]=Dm[k][0]*M[0*3+n]+Dm[k][1]*M[1*3+n]+Dm[k][2]*M[2*3+n];
    for(int k=0;k<3;k++)for(int l=0;l<3;l++) T[k][l]=(U[k][0]*Dm[l][0]+U[k][1]*Dm[l][1]+U[k][2]*Dm[l][2])*2.0f*ssp[b][k*3+l];
    for(int k=0;k<3;k++)for(int n=0;n<3;n++) V[k][n]=Di[k][0]*T[0][n]+Di[k][1]*T[1][n]+Di[k][2]*T[2][n];
    for(int k=0;k<3;k++)for(int l=0;l<3;l++) R[k][l]=V[k][0]*Di[l][0]+V[k][1]*Di[l][1]+V[k][2]*Di[l][2];
    float rr = ratio_p[0];
    float base = rr*4.0f*sf1[b][o]*S1;
    float w2f = (1.0f-rr)*4.0f*sf2[b][o];
    for(int e=0;e<9;e++) weff[(size_t)(b*CC+o)*9+e] = base + w2f*R[e/3][e%3];
  }
  // dsT[(ci*7+k)*64 + co] = ds_w[co, ci, k]
  for(int idx=t; idx<CC*CC*KSZ; idx+=256){
    int co = idx&63; int rest = idx>>6;
    dsT[idx] = dsw[(size_t)co*(CC*KSZ) + rest];
  }
  // offT[(tap*64+ci)*8 + k] = off_w[k, ci, tap]   (k padded to 8)
  for(int idx=t; idx<9*CC*KSZ; idx+=256){
    int tap = idx/(CC*KSZ); int r = idx%(CC*KSZ); int ci = r/KSZ; int k = r%KSZ;
    offT[(size_t)(tap*CC+ci)*8 + k] = offw[((size_t)k*CC + ci)*9 + tap];
  }
}

// ---------------- K3a: HH from x ----------------
__global__ void k_dwt_hh(const float* __restrict__ x, float* __restrict__ HHb){
  int idx = blockIdx.x*256 + threadIdx.x;   // BB*CC*KH*KW = 1048576
  int w = idx & 63; int h = (idx>>6)&63; int bc = idx>>12;
  const float* xp = x + (size_t)bc*HPW;
  float2 r0 = *(const float2*)(xp + (2*h)*WW + 2*w);
  float2 r1 = *(const float2*)(xp + (2*h+1)*WW + 2*w);
  HHb[idx] = 0.5f*(r0.x - r1.x - r0.y + r1.y);
}

// ---------------- K3b: out = 2x + iwt(0,0,0, conv(HH)-HH), NCHW into d_out ----------------
__global__ void k_iwt(const float* __restrict__ HHb, const float* __restrict__ x,
                      const float* __restrict__ weff, float* __restrict__ outb){
  int bc = blockIdx.x;
  float wk[9];
  #pragma unroll
  for(int e=0;e<9;e++) wk[e] = weff[(size_t)bc*9+e];
  const float* Hp = HHb + (size_t)bc*KH*KW;
  const float* xp = x + (size_t)bc*HPW;
  float* op = outb + (size_t)bc*HPW;
  for(int idx=threadIdx.x; idx<KH*KW; idx+=256){
    int h = idx>>6, w = idx&63;
    float acc = 0.f;
    #pragma unroll
    for(int dh=-1;dh<=1;dh++){ int hh=h+dh; if(hh<0||hh>=KH) continue;
      #pragma unroll
      for(int dw=-1;dw<=1;dw++){ int ww=w+dw; if(ww<0||ww>=KW) continue;
        acc += wk[(dh+1)*3+(dw+1)] * Hp[hh*KW+ww]; } }
    float d = 0.5f*(acc - Hp[idx]);
    float2 xr0 = *(const float2*)(xp + (2*h)*WW + 2*w);
    float2 xr1 = *(const float2*)(xp + (2*h+1)*WW + 2*w);
    float2 o0, o1;
    o0.x = 2.f*xr0.x + d;  o0.y = 2.f*xr0.y - d;
    o1.x = 2.f*xr1.x - d;  o1.y = 2.f*xr1.y + d;
    *(float2*)(op + (2*h)*WW + 2*w) = o0;
    *(float2*)(op + (2*h+1)*WW + 2*w) = o1;
  }
}

// ---------------- K3c: transpose NCHW out -> outT[b,h,w,c] ----------------
__global__ void k_transpose(const float* __restrict__ outb, float* __restrict__ outT){
  int b = blockIdx.x >> 7; int h = blockIdx.x & 127;
  __shared__ float tile[CC][WW+1];
  int t = threadIdx.x;
  for(int e=t; e<CC*WW; e+=256){ int c=e>>7, w=e&127; tile[c][w] = outb[((size_t)(b*CC+c)*HH_+h)*WW + w]; }
  __syncthreads();
  float* dst = outT + ((size_t)(b*HH_+h))*WW*CC;
  for(int e=t; e<CC*WW; e+=256){ int w=e>>6, c=e&63; dst[e] = tile[c][w]; }
}

// ---------------- K4: offset conv (7 ch, scalar weights) + BN + tanh + cumsum -> dy ----------------
__global__ __launch_bounds__(256) void k_off(const float* __restrict__ outT,
  const float* __restrict__ offT, const float* __restrict__ offb,
  const float* __restrict__ obg, const float* __restrict__ obb,
  const float* __restrict__ obm, const float* __restrict__ obv,
  float* __restrict__ dyb)
{
  int t = threadIdx.x;
  int pos = blockIdx.x*256 + t;
  int b = pos>>14; int rem = pos&16383; int h = rem>>7; int w = rem&127;
  float acc[KSZ];
  #pragma unroll
  for(int k=0;k<KSZ;k++) acc[k]=offb[k];
  for(int dh=-1;dh<=1;dh++){ int hh=h+dh; if(hh<0||hh>=HH_) continue;   // wave-uniform
    for(int dw=-1;dw<=1;dw++){
      int ww=w+dw; bool wv = (ww>=0)&&(ww<WW);
      int wc = min(max(ww,0),WW-1);
      const float4* p = (const float4*)(outT + ((size_t)((b*HH_+hh)*WW)+wc)*CC);
      const float* wp = offT + (size_t)((dh+1)*3+(dw+1))*CC*8;
      if(wv){
        #pragma unroll
        for(int c4=0;c4<16;c4++){
          float4 v = p[c4];
          const float* wq = wp + c4*32;
          #pragma unroll
          for(int k=0;k<KSZ;k++)
            acc[k] += v.x*wq[k] + v.y*wq[8+k] + v.z*wq[16+k] + v.w*wq[24+k];
        }
      }
    }
  }
  float y[KSZ];
  #pragma unroll
  for(int k=0;k<KSZ;k++){
    float sc = obg[k]*rsqrtf(obv[k]+EPSV);
    float sh = obb[k]-obm[k]*sc;
    y[k] = tanhf(acc[k]*sc+sh);
  }
  float d0 = y[0]+y[1]+y[2], d1=y[1]+y[2], d2=y[2];
  float d4=y[4], d5=y[4]+y[5], d6=y[4]+y[5]+y[6];
  size_t base = ((size_t)b*KSZ)*HPW + rem;
  dyb[base          ] = d0;
  dyb[base +   HPW  ] = d1;
  dyb[base + 2*HPW  ] = d2;
  dyb[base + 3*HPW  ] = 0.f;
  dyb[base + 4*HPW  ] = d4;
  dyb[base + 5*HPW  ] = d5;
  dyb[base + 6*HPW  ] = d6;
}

// ---------------- K5: deform sample + (7x1,stride 7) conv, scalar-weight GEMV ----------------
// grid (2 wsegs, 128 h, 4 b), 256 thr. Lane=pos(64 w), wave=16-co group.
// S[k][ci][pos] in LDS, ci chunked by 32; dsT row (16 co) via uniform s_load.
__global__ __launch_bounds__(256) void k_dsconv(const float* __restrict__ outT,
  const float* __restrict__ dyb, const float* __restrict__ dsT,
  const float* __restrict__ dsb, float* __restrict__ yout)
{
  __shared__ float S[KSZ][32][64];
  int t = threadIdx.x;
  int wseg = blockIdx.x, h = blockIdx.y, b = blockIdx.z;
  // fill-task setup: tasks (k,pos), 448 total; thread t owns e=t and (t<192) e=t+256
  int base0[2], base1[2]; float wrr[2];
  int ntask = (t<192)?2:1;
  #pragma unroll
  for(int i=0;i<2;i++){
    int e = t + i*256;
    if(e<448){
      int k = e>>6, pz = e&63; int w = wseg*64+pz;
      float dv = dyb[((size_t)(b*KSZ+k)*HH_ + h)*WW + w];
      float r = fminf(fmaxf((float)h + dv, 0.f), 127.f);
      float rf = floorf(r); int r0 = (int)rf; float wr = r - rf; int r1 = min(r0+1,127);
      int c = min(max(w + k - 3,0),127);
      base0[i] = ((b*HH_ + r0)*WW + c)*CC;
      base1[i] = ((b*HH_ + r1)*WW + c)*CC;
      wrr[i] = wr;
    } else { base0[i]=0; base1[i]=0; wrr[i]=0.f; }
  }
  int cogrp = __builtin_amdgcn_readfirstlane(t >> 6);
  int pos = t & 63;
  int w = wseg*64 + pos;
  float acc[16];
  #pragma unroll
  for(int u=0;u<16;u++) acc[u]=0.f;

  for(int ch=0; ch<2; ++ch){
    // fill S[k][ci_local][pos]
    #pragma unroll
    for(int i=0;i<2;i++){
      if(i<ntask){
        int e = t + i*256; int k = e>>6; int pz = e&63;
        float wr = wrr[i];
        const float* p0 = outT + base0[i] + ch*32;
        const float* p1 = outT + base1[i] + ch*32;
        #pragma unroll
        for(int q=0;q<8;q++){
          float4 a = *(const float4*)(p0 + q*4);
          float4 bb = *(const float4*)(p1 + q*4);
          S[k][q*4+0][pz] = a.x + wr*(bb.x-a.x);
          S[k][q*4+1][pz] = a.y + wr*(bb.y-a.y);
          S[k][q*4+2][pz] = a.z + wr*(bb.z-a.z);
          S[k][q*4+3][pz] = a.w + wr*(bb.w-a.w);
        }
      }
    }
    __syncthreads();
    // compute: per (k,ci): 1 LDS b32 + 16 scalar floats -> 16 FMAs
    #pragma unroll
    for(int k=0;k<KSZ;k++){
      #pragma unroll 2
      for(int ci=0;ci<32;ci++){
        float sval = S[k][ci][pos];
        const float* dw = dsT + (size_t)(((ch*32+ci)*KSZ + k)*CC) + (cogrp<<4);
        #pragma unroll
        for(int u=0;u<16;u++) acc[u] += dw[u]*sval;
      }
    }
    __syncthreads();
  }
  #pragma unroll
  for(int u=0;u<16;u++){
    int co = (cogrp<<4) + u;
    yout[((size_t)(b*CC+co)*HH_ + h)*WW + w] = acc[u] + dsb[co];
  }
}

// ---------------- K6: GN partial stats per (b,c) ----------------
__global__ void k_gnstat(const float* __restrict__ y, float* __restrict__ stats){
  int bc = blockIdx.x; int t = threadIdx.x;
  const float4* p = (const float4*)(y + (size_t)bc*HPW);
  float s=0.f, q=0.f;
  for(int i=t;i<HPW/4;i+=256){ float4 v=p[i];
    s += v.x+v.y+v.z+v.w; q += v.x*v.x+v.y*v.y+v.z*v.z+v.w*v.w; }
  for(int o=32;o>0;o>>=1){ s += __shfl_down(s,o); q += __shfl_down(q,o); }
  __shared__ float ls[4], lq[4];
  if((t&63)==0){ ls[t>>6]=s; lq[t>>6]=q; }
  __syncthreads();
  if(t==0){ stats[bc*2] = ls[0]+ls[1]+ls[2]+ls[3]; stats[bc*2+1] = lq[0]+lq[1]+lq[2]+lq[3]; }
}

// ---------------- K6b: finalize group stats ----------------
__global__ void k_gnfin(const float* __restrict__ stats, float* __restrict__ gstat){
  int t = threadIdx.x;
  if(t < BB*16){
    int b=t>>4, gp=t&15;
    float s=0.f,q=0.f;
    for(int i=0;i<4;i++){ int bc = b*CC + gp*4 + i; s += stats[bc*2]; q += stats[bc*2+1]; }
    float inv = 1.0f/(4.0f*HPW);
    float mu = s*inv;
    float var = q*inv - mu*mu;
    gstat[t*2] = mu; gstat[t*2+1] = rsqrtf(var+EPSV);
  }
}

// ---------------- K7: apply GN + affine + relu in place ----------------
__global__ void k_gnapply(float* __restrict__ y, const float* __restrict__ gstat,
  const float* __restrict__ gg, const float* __restrict__ gb){
  int idx = blockIdx.x*256 + threadIdx.x;   // float4 index
  float4* p = (float4*)y;
  int bc = idx >> 12;
  int b = bc>>6, c = bc&63;
  int gi = b*16 + (c>>2);
  float mu = gstat[gi*2], rstd = gstat[gi*2+1];
  float sc = rstd*gg[c], sh = gb[c]-mu*sc;
  float4 v = p[idx];
  v.x = fmaxf(v.x*sc+sh, 0.f);
  v.y = fmaxf(v.y*sc+sh, 0.f);
  v.z = fmaxf(v.z*sc+sh, 0.f);
  v.w = fmaxf(v.w*sc+sh, 0.f);
  p[idx] = v;
}

extern "C" void kernel_launch(void* const* d_in, const int* in_sizes, int n_in,
                              void* d_out, int out_size, void* d_ws, size_t ws_size,
                              hipStream_t stream) {
  const float* x      = (const float*)d_in[0];
  const float* weight = (const float*)d_in[1];
  const float* ratio  = (const float*)d_in[2];
  const float* o1fc   = (const float*)d_in[3];
  const float* o1g    = (const float*)d_in[4];
  const float* o1b    = (const float*)d_in[5];
  const float* o1m    = (const float*)d_in[6];
  const float* o1v    = (const float*)d_in[7];
  const float* o1cw   = (const float*)d_in[8];
  const float* o1cb   = (const float*)d_in[9];
  const float* o1fw   = (const float*)d_in[10];
  const float* o1fb   = (const float*)d_in[11];
  const float* o2fc   = (const float*)d_in[12];
  const float* o2g    = (const float*)d_in[13];
  const float* o2b    = (const float*)d_in[14];
  const float* o2m    = (const float*)d_in[15];
  const float* o2v    = (const float*)d_in[16];
  const float* o2cw   = (const float*)d_in[17];
  const float* o2cb   = (const float*)d_in[18];
  const float* o2fw   = (const float*)d_in[19];
  const float* o2fb   = (const float*)d_in[20];
  const float* spw    = (const float*)d_in[21];
  const float* spb    = (const float*)d_in[22];
  const float* offw   = (const float*)d_in[23];
  const float* offb   = (const float*)d_in[24];
  const float* obg    = (const float*)d_in[25];
  const float* obb    = (const float*)d_in[26];
  const float* obm    = (const float*)d_in[27];
  const float* obv    = (const float*)d_in[28];
  const float* dsw    = (const float*)d_in[29];
  const float* dsb    = (const float*)d_in[30];
  const float* gng    = (const float*)d_in[31];
  const float* gnb    = (const float*)d_in[32];

  float* ws    = (float*)d_ws;
  float* outT  = ws;                 // 4194304
  float* HHb   = ws + 4194304;       // 1048576
  float* dyb   = ws + 5242880;       // 458752
  float* gbuf  = ws + 5701632;       // 256
  float* weff  = ws + 5701888;       // 2304
  float* dsT   = ws + 5704192;       // 28672
  float* offT  = ws + 5732864;       // 4608
  float* stats = ws + 5737472;       // 512
  float* gstat = ws + 5737984;       // 128
  float* outb  = (float*)d_out;      // NCHW scratch: out -> y -> final

  k_mean<<<256,256,0,stream>>>(x, gbuf);
  k_dwt_hh<<<4096,256,0,stream>>>(x, HHb);
  k_att<<<1,256,0,stream>>>(gbuf, weight, ratio,
    o1fc,o1g,o1b,o1m,o1v,o1cw,o1cb,o1fw,o1fb,
    o2fc,o2g,o2b,o2m,o2v,o2cw,o2cb,o2fw,o2fb,
    spw,spb, dsw, offw, weff, dsT, offT);
  k_iwt<<<256,256,0,stream>>>(HHb, x, weff, outb);
  k_transpose<<<512,256,0,stream>>>(outb, outT);
  k_off<<<256,256,0,stream>>>(outT, offT, offb, obg, obb, obm, obv, dyb);
  k_dsconv<<<dim3(2,128,4),256,0,stream>>>(outT, dyb, dsT, dsb, outb);
  k_gnstat<<<256,256,0,stream>>>(outb, stats);
  k_gnfin<<<1,64,0,stream>>>(stats, gstat);
  k_gnapply<<<4096,256,0,stream>>>(outb, gstat, gng, gnb);
}

// Round 3
// 176.149 us; speedup vs baseline: 2.1099x; 1.7133x over previous
//
#include <hip/hip_runtime.h>
#include <math.h>

#define BB 4
#define CC 64
#define HH_ 128
#define WW 128
#define HPW (HH_*WW)     // 16384
#define KH 64
#define KW 64
#define KSZ 7
#define AA 16
#define EPSV 1e-5f
#define KTOT 448         // KSZ*CC... K = k*64+ci

typedef __attribute__((ext_vector_type(8))) short bf16x8;
typedef __attribute__((ext_vector_type(4))) float f32x4;
typedef unsigned short ushort_t;

__device__ __forceinline__ float sigm(float x){ return 1.0f/(1.0f+expf(-x)); }
__device__ __forceinline__ unsigned short f2bf(float f){
  unsigned u = __float_as_uint(f);
  return (unsigned short)((u + 0x7fffu + ((u>>16)&1u)) >> 16);
}

// ---------------- K1: per-(b,c) mean of x ----------------
__global__ void k_mean(const float* __restrict__ x, float* __restrict__ g){
  int bc = blockIdx.x; int t = threadIdx.x;
  const float4* p = (const float4*)(x + (size_t)bc*HPW);
  float s = 0.f;
  for(int i=t;i<HPW/4;i+=256){ float4 v = p[i]; s += v.x+v.y+v.z+v.w; }
  for(int o=32;o>0;o>>=1) s += __shfl_down(s,o);
  __shared__ float ls[4];
  if((t&63)==0) ls[t>>6]=s;
  __syncthreads();
  if(t==0) g[bc] = (ls[0]+ls[1]+ls[2]+ls[3]) * (1.0f/HPW);
}

// ---------------- K2: attention + weff + dsWbf(bf16) + offL ----------------
__global__ void k_att(const float* __restrict__ g, const float* __restrict__ w,
  const float* __restrict__ ratio_p,
  const float* __restrict__ o1fc, const float* __restrict__ o1g,const float* __restrict__ o1b,
  const float* __restrict__ o1m,const float* __restrict__ o1v,
  const float* __restrict__ o1cw,const float* __restrict__ o1cb,
  const float* __restrict__ o1fw,const float* __restrict__ o1fb,
  const float* __restrict__ o2fc, const float* __restrict__ o2g,const float* __restrict__ o2b,
  const float* __restrict__ o2m,const float* __restrict__ o2v,
  const float* __restrict__ o2cw,const float* __restrict__ o2cb,
  const float* __restrict__ o2fw,const float* __restrict__ o2fb,
  const float* __restrict__ spw,const float* __restrict__ spb,
  const float* __restrict__ dsw, const float* __restrict__ offw,
  float* __restrict__ weff, ushort_t* __restrict__ dsWbf, float* __restrict__ offL)
{
  __shared__ float sg[BB][CC], sa1[BB][AA], sa2[BB][AA];
  __shared__ float sc1[BB][CC], sf1[BB][CC], sc2[BB][CC], sf2[BB][CC], ssp[BB][9];
  int t = threadIdx.x;
  sg[t>>6][t&63] = g[t];
  __syncthreads();
  if(t < BB*AA){
    int b=t/AA, j=t%AA;
    float v1=0.f, v2=0.f;
    for(int c=0;c<CC;c++){ float gv = sg[b][c]; v1 += gv*o1fc[j*CC+c]; v2 += gv*o2fc[j*CC+c]; }
    v1 = (v1-o1m[j])*rsqrtf(o1v[j]+EPSV)*o1g[j]+o1b[j]; sa1[b][j]=fmaxf(v1,0.f);
    v2 = (v2-o2m[j])*rsqrtf(o2v[j]+EPSV)*o2g[j]+o2b[j]; sa2[b][j]=fmaxf(v2,0.f);
  }
  __syncthreads();
  { int b=t>>6, c=t&63;
    float d1=o1cb[c], d2=o1fb[c], d3=o2cb[c], d4=o2fb[c];
    for(int j=0;j<AA;j++){
      float a1=sa1[b][j], a2=sa2[b][j];
      d1+=a1*o1cw[c*AA+j]; d2+=a1*o1fw[c*AA+j];
      d3+=a2*o2cw[c*AA+j]; d4+=a2*o2fw[c*AA+j];
    }
    sc1[b][c]=sigm(d1); sf1[b][c]=sigm(d2); sc2[b][c]=sigm(d3); sf2[b][c]=sigm(d4);
  }
  if(t < BB*9){ int b=t/9,k=t%9; float d=spb[k]; for(int j=0;j<AA;j++) d+=sa2[b][j]*spw[k*AA+j]; ssp[b][k]=sigm(d); }
  __syncthreads();
  {
    int b=t>>6, o=t&63;
    float S1=0.f; float M[9];
    for(int e=0;e<9;e++) M[e]=0.f;
    for(int i=0;i<CC;i++){
      const float* wp = w + ((size_t)(o*CC+i))*9;
      float w9[9]; float m=0.f;
      #pragma unroll
      for(int e=0;e<9;e++){ w9[e]=wp[e]; m+=w9[e]; }
      m *= (1.0f/9.0f);
      S1 += m * sc1[b][i];
      float c2v = sc2[b][i];
      #pragma unroll
      for(int e=0;e<9;e++) M[e] += (w9[e]-m)*c2v;
    }
    const float Dm[3][3] = {{2.f,2.f,2.f},{1.7320508075688772f,0.f,-1.7320508075688772f},{1.f,-2.f,1.f}};
    const float Di[3][3] = {{0.16666666666666666f,0.28867513459481287f,0.16666666666666666f},
                            {0.16666666666666666f,0.f,-0.3333333333333333f},
                            {0.16666666666666666f,-0.28867513459481287f,0.16666666666666666f}};
    float U[3][3], T[3][3], V[3][3], R[3][3];
    for(int k=0;k<3;k++)for(int n=0;n<3;n++) U[k][n]=Dm[k][0]*M[0*3+n]+Dm[k][1]*M[1*3+n]+Dm[k][2]*M[2*3+n];
    for(int k=0;k<3;k++)for(int l=0;l<3;l++) T[k][l]=(U[k][0]*Dm[l][0]+U[k][1]*Dm[l][1]+U[k][2]*Dm[l][2])*2.0f*ssp[b][k*3+l];
    for(int k=0;k<3;k++)for(int n=0;n<3;n++) V[k][n]=Di[k][0]*T[0][n]+Di[k][1]*T[1][n]+Di[k][2]*T[2][n];
    for(int k=0;k<3;k++)for(int l=0;l<3;l++) R[k][l]=V[k][0]*Di[l][0]+V[k][1]*Di[l][1]+V[k][2]*Di[l][2];
    float rr = ratio_p[0];
    float base = rr*4.0f*sf1[b][o]*S1;
    float w2f = (1.0f-rr)*4.0f*sf2[b][o];
    for(int e=0;e<9;e++) weff[(size_t)(b*CC+o)*9+e] = base + w2f*R[e/3][e%3];
  }
  // dsWbf[co*448 + k*64 + ci] = bf16(dsw[(co*64+ci)*7 + k])
  for(int idx=t; idx<CC*KTOT; idx+=256){
    int co = idx/KTOT; int K = idx%KTOT; int k = K>>6; int ci = K&63;
    dsWbf[idx] = f2bf(dsw[(size_t)(co*CC+ci)*KSZ + k]);
  }
  // offL[((tap*16+c4)*8+k)*4+j] = offw[k, ci=c4*4+j, tap], k<7 else 0
  for(int idx=t; idx<9*16*8*4; idx+=256){
    int j = idx&3; int k = (idx>>2)&7; int c4 = (idx>>5)&15; int tap = idx>>9;
    float v = 0.f;
    if(k<KSZ) v = offw[((size_t)k*CC + (c4*4+j))*9 + tap];
    offL[idx] = v;
  }
}

// ---------------- K3a: HH from x ----------------
__global__ void k_dwt_hh(const float* __restrict__ x, float* __restrict__ HHb){
  int idx = blockIdx.x*256 + threadIdx.x;   // BB*CC*KH*KW = 1048576
  int w = idx & 63; int h = (idx>>6)&63; int bc = idx>>12;
  const float* xp = x + (size_t)bc*HPW;
  float2 r0 = *(const float2*)(xp + (2*h)*WW + 2*w);
  float2 r1 = *(const float2*)(xp + (2*h+1)*WW + 2*w);
  HHb[idx] = 0.5f*(r0.x - r1.x - r0.y + r1.y);
}

// ---------------- K3b: out = 2x + iwt(0,0,0, conv(HH)-HH) ----------------
__global__ void k_iwt(const float* __restrict__ HHb, const float* __restrict__ x,
                      const float* __restrict__ weff, float* __restrict__ outb){
  int bc = blockIdx.x;
  float wk[9];
  #pragma unroll
  for(int e=0;e<9;e++) wk[e] = weff[(size_t)bc*9+e];
  const float* Hp = HHb + (size_t)bc*KH*KW;
  const float* xp = x + (size_t)bc*HPW;
  float* op = outb + (size_t)bc*HPW;
  for(int idx=threadIdx.x; idx<KH*KW; idx+=256){
    int h = idx>>6, w = idx&63;
    float acc = 0.f;
    #pragma unroll
    for(int dh=-1;dh<=1;dh++){ int hh=h+dh; if(hh<0||hh>=KH) continue;
      #pragma unroll
      for(int dw=-1;dw<=1;dw++){ int ww=w+dw; if(ww<0||ww>=KW) continue;
        acc += wk[(dh+1)*3+(dw+1)] * Hp[hh*KW+ww]; } }
    float d = 0.5f*(acc - Hp[idx]);
    float2 xr0 = *(const float2*)(xp + (2*h)*WW + 2*w);
    float2 xr1 = *(const float2*)(xp + (2*h+1)*WW + 2*w);
    float2 o0, o1;
    o0.x = 2.f*xr0.x + d;  o0.y = 2.f*xr0.y - d;
    o1.x = 2.f*xr1.x - d;  o1.y = 2.f*xr1.y + d;
    *(float2*)(op + (2*h)*WW + 2*w) = o0;
    *(float2*)(op + (2*h+1)*WW + 2*w) = o1;
  }
}

// ---------------- K3c: transpose NCHW out -> outT[b,h,w,c] ----------------
__global__ void k_transpose(const float* __restrict__ outb, float* __restrict__ outT){
  int b = blockIdx.x >> 7; int h = blockIdx.x & 127;
  __shared__ float tile[CC][WW+1];
  int t = threadIdx.x;
  for(int e=t; e<CC*WW; e+=256){ int c=e>>7, w=e&127; tile[c][w] = outb[((size_t)(b*CC+c)*HH_+h)*WW + w]; }
  __syncthreads();
  float* dst = outT + ((size_t)(b*HH_+h))*WW*CC;
  for(int e=t; e<CC*WW; e+=256){ int w=e>>6, c=e&63; dst[e] = tile[c][w]; }
}

// ---------------- K4: offset conv via LDS-broadcast weights ----------------
__global__ __launch_bounds__(256) void k_off(const float* __restrict__ outT,
  const float* __restrict__ offL, const float* __restrict__ offb,
  const float* __restrict__ obg, const float* __restrict__ obb,
  const float* __restrict__ obm, const float* __restrict__ obv,
  float* __restrict__ dyb)
{
  __shared__ float sw[9*16*8*4];   // 18KB: [tap][c4][k8][ci4]
  int t = threadIdx.x;
  for(int i=t;i<9*16*8*4;i+=256) sw[i]=offL[i];
  __syncthreads();
  int pos = blockIdx.x*256 + t;
  int b = pos>>14; int rem = pos&16383; int h = rem>>7; int w = rem&127;
  float acc[KSZ];
  #pragma unroll
  for(int k=0;k<KSZ;k++) acc[k]=offb[k];
  for(int dh=-1;dh<=1;dh++){ int hh=h+dh; if(hh<0||hh>=HH_) continue;   // wave-uniform
    for(int dw=-1;dw<=1;dw++){
      int ww=w+dw; bool wv = (ww>=0)&&(ww<WW);
      int wc = min(max(ww,0),WW-1);
      const float4* p = (const float4*)(outT + ((size_t)((b*HH_+hh)*WW)+wc)*CC);
      const float* wp = sw + ((dh+1)*3+(dw+1))*16*8*4;
      if(wv){
        #pragma unroll 4
        for(int c4=0;c4<16;c4++){
          float4 v = p[c4];
          const float* wq = wp + c4*32;
          #pragma unroll
          for(int k=0;k<KSZ;k++)
            acc[k] += v.x*wq[k*4+0] + v.y*wq[k*4+1] + v.z*wq[k*4+2] + v.w*wq[k*4+3];
        }
      }
    }
  }
  float y[KSZ];
  #pragma unroll
  for(int k=0;k<KSZ;k++){
    float sc = obg[k]*rsqrtf(obv[k]+EPSV);
    float sh = obb[k]-obm[k]*sc;
    y[k] = tanhf(acc[k]*sc+sh);
  }
  float d0 = y[0]+y[1]+y[2], d1=y[1]+y[2], d2=y[2];
  float d4=y[4], d5=y[4]+y[5], d6=y[4]+y[5]+y[6];
  size_t base = ((size_t)b*KSZ)*HPW + rem;
  dyb[base          ] = d0;
  dyb[base +   HPW  ] = d1;
  dyb[base + 2*HPW  ] = d2;
  dyb[base + 3*HPW  ] = 0.f;
  dyb[base + 4*HPW  ] = d4;
  dyb[base + 5*HPW  ] = d5;
  dyb[base + 6*HPW  ] = d6;
}

// ---------------- K5: deform sample + 7x1 conv as bf16 MFMA GEMM ----------------
// grid (wseg=2, h=128, b=4), 256 thr. Per block: C[64co x 64w] = W[64 x 448] * S[448 x 64w]
// S_T[pos 64][K 448] bf16 in LDS, XOR-swizzled; A-frags from dsWbf (global, L2-hot).
__global__ __launch_bounds__(256) void k_dsconv(const float* __restrict__ outT,
  const float* __restrict__ dyb, const ushort_t* __restrict__ dsWbf,
  const float* __restrict__ dsb, float* __restrict__ yout)
{
  __shared__ ushort_t S[64*KTOT];      // 57344 B
  __shared__ int sb0[KTOT], sb1[KTOT]; // sample row bases
  __shared__ float swr[KTOT];
  int t = threadIdx.x;
  int wseg = blockIdx.x, h = blockIdx.y, b = blockIdx.z;
  // phase 0: per-task (e = k*64+pos) sample coords
  #pragma unroll
  for(int i=0;i<2;i++){
    int e = t + i*256;
    if(e<KTOT){
      int k = e>>6, pz = e&63; int w = wseg*64+pz;
      float dv = dyb[((size_t)(b*KSZ+k)*HH_ + h)*WW + w];
      float r = fminf(fmaxf((float)h + dv, 0.f), 127.f);
      float rf = floorf(r); int r0 = (int)rf; float wr = r - rf; int r1 = min(r0+1,127);
      int c = min(max(w + k - 3,0),127);
      sb0[e] = ((b*HH_ + r0)*WW + c)*CC;
      sb1[e] = ((b*HH_ + r1)*WW + c)*CC;
      swr[e] = wr;
    }
  }
  // A-frag preload (independent of LDS): wave wid -> co tile
  int wid = t>>6, lane = t&63;
  int arow = lane&15, kgrp = lane>>4;
  bf16x8 aF[14];
  const ushort_t* Wp = dsWbf + (size_t)((wid<<4)+arow)*KTOT + kgrp*8;
  #pragma unroll
  for(int ks=0;ks<14;ks++) aF[ks] = *(const bf16x8*)(Wp + ks*32);
  __syncthreads();
  // phase 1: fill S_T (lane = ci, coalesced 256B reads)
  for(int e=wid; e<KTOT; e+=4){
    int b0 = sb0[e], b1 = sb1[e]; float wr = swr[e];
    float a = outT[b0 + lane];
    float bb = outT[b1 + lane];
    float v = a + wr*(bb-a);
    int pz = e&63; int k = e>>6;
    int idx = pz*KTOT + (k<<6) + lane;      // short index
    S[idx ^ ((pz&7)<<3)] = f2bf(v);         // byte ^= (pz&7)<<4
  }
  __syncthreads();
  // phase 2: MFMA. wave wid owns co[wid*16..+15], all 4 N-tiles.
  f32x4 acc[4];
  #pragma unroll
  for(int nt=0;nt<4;nt++) acc[nt] = (f32x4){0.f,0.f,0.f,0.f};
  #pragma unroll
  for(int nt=0;nt<4;nt++){
    int posb = nt*16 + arow;
    #pragma unroll
    for(int ks=0;ks<14;ks++){
      int off = (posb*(KTOT*2) + ks*64 + kgrp*16) ^ ((posb&7)<<4);
      bf16x8 bF = *(const bf16x8*)((const char*)S + off);
      acc[nt] = __builtin_amdgcn_mfma_f32_16x16x32_bf16(aF[ks], bF, acc[nt], 0,0,0);
    }
  }
  // phase 3: store C: lane holds C[row=kgrp*4+r][col=arow]
  #pragma unroll
  for(int r=0;r<4;r++){
    int co = (wid<<4) + kgrp*4 + r;
    float bias = dsb[co];
    #pragma unroll
    for(int nt=0;nt<4;nt++){
      int wcol = wseg*64 + nt*16 + arow;
      yout[((size_t)(b*CC+co)*HH_ + h)*WW + wcol] = acc[nt][r] + bias;
    }
  }
}

// ---------------- K6: GN partial stats per (b,c) ----------------
__global__ void k_gnstat(const float* __restrict__ y, float* __restrict__ stats){
  int bc = blockIdx.x; int t = threadIdx.x;
  const float4* p = (const float4*)(y + (size_t)bc*HPW);
  float s=0.f, q=0.f;
  for(int i=t;i<HPW/4;i+=256){ float4 v=p[i];
    s += v.x+v.y+v.z+v.w; q += v.x*v.x+v.y*v.y+v.z*v.z+v.w*v.w; }
  for(int o=32;o>0;o>>=1){ s += __shfl_down(s,o); q += __shfl_down(q,o); }
  __shared__ float ls[4], lq[4];
  if((t&63)==0){ ls[t>>6]=s; lq[t>>6]=q; }
  __syncthreads();
  if(t==0){ stats[bc*2] = ls[0]+ls[1]+ls[2]+ls[3]; stats[bc*2+1] = lq[0]+lq[1]+lq[2]+lq[3]; }
}

// ---------------- K6b: finalize group stats ----------------
__global__ void k_gnfin(const float* __restrict__ stats, float* __restrict__ gstat){
  int t = threadIdx.x;
  if(t < BB*16){
    int b=t>>4, gp=t&15;
    float s=0.f,q=0.f;
    for(int i=0;i<4;i++){ int bc = b*CC + gp*4 + i; s += stats[bc*2]; q += stats[bc*2+1]; }
    float inv = 1.0f/(4.0f*HPW);
    float mu = s*inv;
    float var = q*inv - mu*mu;
    gstat[t*2] = mu; gstat[t*2+1] = rsqrtf(var+EPSV);
  }
}

// ---------------- K7: apply GN + affine + relu in place ----------------
__global__ void k_gnapply(float* __restrict__ y, const float* __restrict__ gstat,
  const float* __restrict__ gg, const float* __restrict__ gb){
  int idx = blockIdx.x*256 + threadIdx.x;   // float4 index
  float4* p = (float4*)y;
  int bc = idx >> 12;
  int b = bc>>6, c = bc&63;
  int gi = b*16 + (c>>2);
  float mu = gstat[gi*2], rstd = gstat[gi*2+1];
  float sc = rstd*gg[c], sh = gb[c]-mu*sc;
  float4 v = p[idx];
  v.x = fmaxf(v.x*sc+sh, 0.f);
  v.y = fmaxf(v.y*sc+sh, 0.f);
  v.z = fmaxf(v.z*sc+sh, 0.f);
  v.w = fmaxf(v.w*sc+sh, 0.f);
  p[idx] = v;
}

extern "C" void kernel_launch(void* const* d_in, const int* in_sizes, int n_in,
                              void* d_out, int out_size, void* d_ws, size_t ws_size,
                              hipStream_t stream) {
  const float* x      = (const float*)d_in[0];
  const float* weight = (const float*)d_in[1];
  const float* ratio  = (const float*)d_in[2];
  const float* o1fc   = (const float*)d_in[3];
  const float* o1g    = (const float*)d_in[4];
  const float* o1b    = (const float*)d_in[5];
  const float* o1m    = (const float*)d_in[6];
  const float* o1v    = (const float*)d_in[7];
  const float* o1cw   = (const float*)d_in[8];
  const float* o1cb   = (const float*)d_in[9];
  const float* o1fw   = (const float*)d_in[10];
  const float* o1fb   = (const float*)d_in[11];
  const float* o2fc   = (const float*)d_in[12];
  const float* o2g    = (const float*)d_in[13];
  const float* o2b    = (const float*)d_in[14];
  const float* o2m    = (const float*)d_in[15];
  const float* o2v    = (const float*)d_in[16];
  const float* o2cw   = (const float*)d_in[17];
  const float* o2cb   = (const float*)d_in[18];
  const float* o2fw   = (const float*)d_in[19];
  const float* o2fb   = (const float*)d_in[20];
  const float* spw    = (const float*)d_in[21];
  const float* spb    = (const float*)d_in[22];
  const float* offw   = (const float*)d_in[23];
  const float* offb   = (const float*)d_in[24];
  const float* obg    = (const float*)d_in[25];
  const float* obb    = (const float*)d_in[26];
  const float* obm    = (const float*)d_in[27];
  const float* obv    = (const float*)d_in[28];
  const float* dsw    = (const float*)d_in[29];
  const float* dsb    = (const float*)d_in[30];
  const float* gng    = (const float*)d_in[31];
  const float* gnb    = (const float*)d_in[32];

  float* ws    = (float*)d_ws;
  float* outT  = ws;                 // 4194304
  float* HHb   = ws + 4194304;       // 1048576
  float* dyb   = ws + 5242880;       // 458752
  float* gbuf  = ws + 5701632;       // 256
  float* weff  = ws + 5701888;       // 2304
  ushort_t* dsWbf = (ushort_t*)(ws + 5704192); // 28672 shorts = 14336 floats
  float* offL  = ws + 5718528;       // 4608
  float* stats = ws + 5723136;       // 512
  float* gstat = ws + 5723648;       // 128
  float* outb  = (float*)d_out;      // NCHW scratch: out -> y -> final

  k_mean<<<256,256,0,stream>>>(x, gbuf);
  k_dwt_hh<<<4096,256,0,stream>>>(x, HHb);
  k_att<<<1,256,0,stream>>>(gbuf, weight, ratio,
    o1fc,o1g,o1b,o1m,o1v,o1cw,o1cb,o1fw,o1fb,
    o2fc,o2g,o2b,o2m,o2v,o2cw,o2cb,o2fw,o2fb,
    spw,spb, dsw, offw, weff, dsWbf, offL);
  k_iwt<<<256,256,0,stream>>>(HHb, x, weff, outb);
  k_transpose<<<512,256,0,stream>>>(outb, outT);
  k_off<<<256,256,0,stream>>>(outT, offL, offb, obg, obb, obm, obv, dyb);
  k_dsconv<<<dim3(2,128,4),256,0,stream>>>(outT, dyb, dsWbf, dsb, outb);
  k_gnstat<<<256,256,0,stream>>>(outb, stats);
  k_gnfin<<<1,64,0,stream>>>(stats, gstat);
  k_gnapply<<<4096,256,0,stream>>>(outb, gstat, gng, gnb);
}

// Round 4
// 146.743 us; speedup vs baseline: 2.5327x; 1.2004x over previous
//
#include <hip/hip_runtime.h>
#include <math.h>

#define BB 4
#define CC 64
#define HH_ 128
#define WW 128
#define HPW (HH_*WW)     // 16384
#define KH 64
#define KW 64
#define KSZ 7
#define AA 16
#define EPSV 1e-5f
#define KTOT 448         // KSZ*CC... K = k*64+ci

typedef __attribute__((ext_vector_type(8))) short bf16x8;
typedef __attribute__((ext_vector_type(4))) float f32x4;
typedef unsigned short ushort_t;

__device__ __forceinline__ float sigm(float x){ return 1.0f/(1.0f+expf(-x)); }
__device__ __forceinline__ unsigned short f2bf(float f){
  unsigned u = __float_as_uint(f);
  return (unsigned short)((u + 0x7fffu + ((u>>16)&1u)) >> 16);
}

// attn ws layout: sc1[4][64] @0, sf1 @256, sc2 @512, sf2 @768, ssp[4][9] @1024

// ---------------- K1: per-(b,c) mean of x ----------------
__global__ void k_mean(const float* __restrict__ x, float* __restrict__ g){
  int bc = blockIdx.x; int t = threadIdx.x;
  const float4* p = (const float4*)(x + (size_t)bc*HPW);
  float s = 0.f;
  for(int i=t;i<HPW/4;i+=256){ float4 v = p[i]; s += v.x+v.y+v.z+v.w; }
  for(int o=32;o>0;o>>=1) s += __shfl_down(s,o);
  __shared__ float ls[4];
  if((t&63)==0) ls[t>>6]=s;
  __syncthreads();
  if(t==0) g[bc] = (ls[0]+ls[1]+ls[2]+ls[3]) * (1.0f/HPW);
}

// ---------------- K2a: attention scalars (1 block, LDS-staged) ----------------
__global__ __launch_bounds__(256) void k_att1(const float* __restrict__ g,
  const float* __restrict__ o1fc, const float* __restrict__ o1g,const float* __restrict__ o1b,
  const float* __restrict__ o1m,const float* __restrict__ o1v,
  const float* __restrict__ o1cw,const float* __restrict__ o1cb,
  const float* __restrict__ o1fw,const float* __restrict__ o1fb,
  const float* __restrict__ o2fc, const float* __restrict__ o2g,const float* __restrict__ o2b,
  const float* __restrict__ o2m,const float* __restrict__ o2v,
  const float* __restrict__ o2cw,const float* __restrict__ o2cb,
  const float* __restrict__ o2fw,const float* __restrict__ o2fb,
  const float* __restrict__ spw,const float* __restrict__ spb,
  float* __restrict__ attn)
{
  __shared__ float sg[BB*CC], sfc1[AA*CC], sfc2[AA*CC];
  __shared__ float scw1[CC*AA], sfw1[CC*AA], scw2[CC*AA], sfw2[CC*AA];
  __shared__ float sa1[BB][AA], sa2[BB][AA];
  int t = threadIdx.x;
  sg[t] = g[t];
  for(int i=t;i<AA*CC;i+=256){
    sfc1[i]=o1fc[i]; sfc2[i]=o2fc[i];
    scw1[i]=o1cw[i]; sfw1[i]=o1fw[i];
    scw2[i]=o2cw[i]; sfw2[i]=o2fw[i];
  }
  __syncthreads();
  if(t < BB*AA){
    int b=t>>4, j=t&15;
    float v1=0.f, v2=0.f;
    for(int c=0;c<CC;c++){ float gv = sg[b*CC+c]; v1 += gv*sfc1[j*CC+c]; v2 += gv*sfc2[j*CC+c]; }
    v1 = (v1-o1m[j])*rsqrtf(o1v[j]+EPSV)*o1g[j]+o1b[j]; sa1[b][j]=fmaxf(v1,0.f);
    v2 = (v2-o2m[j])*rsqrtf(o2v[j]+EPSV)*o2g[j]+o2b[j]; sa2[b][j]=fmaxf(v2,0.f);
  }
  __syncthreads();
  { int b=t>>6, c=t&63;
    float d1=o1cb[c], d2=o1fb[c], d3=o2cb[c], d4=o2fb[c];
    #pragma unroll
    for(int j=0;j<AA;j++){
      float a1=sa1[b][j], a2=sa2[b][j];
      d1+=a1*scw1[c*AA+j]; d2+=a1*sfw1[c*AA+j];
      d3+=a2*scw2[c*AA+j]; d4+=a2*sfw2[c*AA+j];
    }
    attn[      t]=sigm(d1); attn[256+ t]=sigm(d2);
    attn[512+  t]=sigm(d3); attn[768+ t]=sigm(d4);
  }
  if(t < BB*9){
    int b=t/9,k=t%9; float d=spb[k];
    #pragma unroll
    for(int j=0;j<AA;j++) d+=sa2[b][j]*spw[k*AA+j];
    attn[1024+t]=sigm(d);
  }
}

// ---------------- K2b: weff, grid (b,o), 64 thr = ci ----------------
__global__ __launch_bounds__(64) void k_weff(const float* __restrict__ w,
  const float* __restrict__ attn, const float* __restrict__ ratio_p,
  float* __restrict__ weff)
{
  int bo = blockIdx.x; int b = bo>>6, o = bo&63; int ci = threadIdx.x;
  const float* wp = w + (size_t)(o*CC+ci)*9;
  float w9[9]; float m=0.f;
  #pragma unroll
  for(int e=0;e<9;e++){ w9[e]=wp[e]; m+=w9[e]; }
  m *= (1.0f/9.0f);
  float S1 = m * attn[b*CC+ci];           // sc1
  float c2v = attn[512 + b*CC+ci];        // sc2
  float M[9];
  #pragma unroll
  for(int e=0;e<9;e++) M[e] = (w9[e]-m)*c2v;
  #pragma unroll
  for(int off=32; off>0; off>>=1){
    S1 += __shfl_xor(S1, off);
    #pragma unroll
    for(int e=0;e<9;e++) M[e] += __shfl_xor(M[e], off);
  }
  if(ci==0){
    const float Dm[3][3] = {{2.f,2.f,2.f},{1.7320508075688772f,0.f,-1.7320508075688772f},{1.f,-2.f,1.f}};
    const float Di[3][3] = {{0.16666666666666666f,0.28867513459481287f,0.16666666666666666f},
                            {0.16666666666666666f,0.f,-0.3333333333333333f},
                            {0.16666666666666666f,-0.28867513459481287f,0.16666666666666666f}};
    float U[3][3], T[3][3], V[3][3], R[3][3];
    for(int k=0;k<3;k++)for(int n=0;n<3;n++) U[k][n]=Dm[k][0]*M[0*3+n]+Dm[k][1]*M[1*3+n]+Dm[k][2]*M[2*3+n];
    for(int k=0;k<3;k++)for(int l=0;l<3;l++) T[k][l]=(U[k][0]*Dm[l][0]+U[k][1]*Dm[l][1]+U[k][2]*Dm[l][2])*2.0f*attn[1024+b*9+k*3+l];
    for(int k=0;k<3;k++)for(int n=0;n<3;n++) V[k][n]=Di[k][0]*T[0][n]+Di[k][1]*T[1][n]+Di[k][2]*T[2][n];
    for(int k=0;k<3;k++)for(int l=0;l<3;l++) R[k][l]=V[k][0]*Di[l][0]+V[k][1]*Di[l][1]+V[k][2]*Di[l][2];
    float rr = ratio_p[0];
    float base = rr*4.0f*attn[256+b*CC+o]*S1;        // sf1
    float w2f = (1.0f-rr)*4.0f*attn[768+b*CC+o];     // sf2
    #pragma unroll
    for(int e=0;e<9;e++) weff[(size_t)bo*9+e] = base + w2f*R[e/3][e%3];
  }
}

// ---------------- K2c: weight format prep (grid-parallel) ----------------
__global__ void k_prep(const float* __restrict__ dsw, const float* __restrict__ offw,
                       ushort_t* __restrict__ dsWbf, float* __restrict__ offL){
  int idx = blockIdx.x*256 + threadIdx.x;
  if(idx < CC*KTOT){
    // dsWbf[co*448 + k*64 + ci] = bf16(dsw[(co*64+ci)*7 + k])
    int co = idx/KTOT; int K = idx%KTOT; int k = K>>6; int ci = K&63;
    dsWbf[idx] = f2bf(dsw[(size_t)(co*CC+ci)*KSZ + k]);
  } else {
    int j2 = idx - CC*KTOT;
    if(j2 < 9*16*8*4){
      // offL[((tap*16+c4)*8+k)*4+j] = offw[k, ci=c4*4+j, tap], k<7 else 0
      int j = j2&3; int k = (j2>>2)&7; int c4 = (j2>>5)&15; int tap = j2>>9;
      float v = 0.f;
      if(k<KSZ) v = offw[((size_t)k*CC + (c4*4+j))*9 + tap];
      offL[j2] = v;
    }
  }
}

// ---------------- K3a: HH from x ----------------
__global__ void k_dwt_hh(const float* __restrict__ x, float* __restrict__ HHb){
  int idx = blockIdx.x*256 + threadIdx.x;   // BB*CC*KH*KW = 1048576
  int w = idx & 63; int h = (idx>>6)&63; int bc = idx>>12;
  const float* xp = x + (size_t)bc*HPW;
  float2 r0 = *(const float2*)(xp + (2*h)*WW + 2*w);
  float2 r1 = *(const float2*)(xp + (2*h+1)*WW + 2*w);
  HHb[idx] = 0.5f*(r0.x - r1.x - r0.y + r1.y);
}

// ---------------- K3b: out = 2x + iwt(0,0,0, conv(HH)-HH) ----------------
__global__ void k_iwt(const float* __restrict__ HHb, const float* __restrict__ x,
                      const float* __restrict__ weff, float* __restrict__ outb){
  int bc = blockIdx.x;
  float wk[9];
  #pragma unroll
  for(int e=0;e<9;e++) wk[e] = weff[(size_t)bc*9+e];
  const float* Hp = HHb + (size_t)bc*KH*KW;
  const float* xp = x + (size_t)bc*HPW;
  float* op = outb + (size_t)bc*HPW;
  for(int idx=threadIdx.x; idx<KH*KW; idx+=256){
    int h = idx>>6, w = idx&63;
    float acc = 0.f;
    #pragma unroll
    for(int dh=-1;dh<=1;dh++){ int hh=h+dh; if(hh<0||hh>=KH) continue;
      #pragma unroll
      for(int dw=-1;dw<=1;dw++){ int ww=w+dw; if(ww<0||ww>=KW) continue;
        acc += wk[(dh+1)*3+(dw+1)] * Hp[hh*KW+ww]; } }
    float d = 0.5f*(acc - Hp[idx]);
    float2 xr0 = *(const float2*)(xp + (2*h)*WW + 2*w);
    float2 xr1 = *(const float2*)(xp + (2*h+1)*WW + 2*w);
    float2 o0, o1;
    o0.x = 2.f*xr0.x + d;  o0.y = 2.f*xr0.y - d;
    o1.x = 2.f*xr1.x - d;  o1.y = 2.f*xr1.y + d;
    *(float2*)(op + (2*h)*WW + 2*w) = o0;
    *(float2*)(op + (2*h+1)*WW + 2*w) = o1;
  }
}

// ---------------- K3c: transpose NCHW out -> outT[b,h,w,c] ----------------
__global__ void k_transpose(const float* __restrict__ outb, float* __restrict__ outT){
  int b = blockIdx.x >> 7; int h = blockIdx.x & 127;
  __shared__ float tile[CC][WW+1];
  int t = threadIdx.x;
  for(int e=t; e<CC*WW; e+=256){ int c=e>>7, w=e&127; tile[c][w] = outb[((size_t)(b*CC+c)*HH_+h)*WW + w]; }
  __syncthreads();
  float* dst = outT + ((size_t)(b*HH_+h))*WW*CC;
  for(int e=t; e<CC*WW; e+=256){ int w=e>>6, c=e&63; dst[e] = tile[c][w]; }
}

// ---------------- K4: offset conv via LDS-broadcast weights ----------------
__global__ __launch_bounds__(256) void k_off(const float* __restrict__ outT,
  const float* __restrict__ offL, const float* __restrict__ offb,
  const float* __restrict__ obg, const float* __restrict__ obb,
  const float* __restrict__ obm, const float* __restrict__ obv,
  float* __restrict__ dyb)
{
  __shared__ float sw[9*16*8*4];   // 18KB: [tap][c4][k8][ci4]
  int t = threadIdx.x;
  for(int i=t;i<9*16*8*4;i+=256) sw[i]=offL[i];
  __syncthreads();
  int pos = blockIdx.x*256 + t;
  int b = pos>>14; int rem = pos&16383; int h = rem>>7; int w = rem&127;
  float acc[KSZ];
  #pragma unroll
  for(int k=0;k<KSZ;k++) acc[k]=offb[k];
  for(int dh=-1;dh<=1;dh++){ int hh=h+dh; if(hh<0||hh>=HH_) continue;   // wave-uniform
    for(int dw=-1;dw<=1;dw++){
      int ww=w+dw; bool wv = (ww>=0)&&(ww<WW);
      int wc = min(max(ww,0),WW-1);
      const float4* p = (const float4*)(outT + ((size_t)((b*HH_+hh)*WW)+wc)*CC);
      const float* wp = sw + ((dh+1)*3+(dw+1))*16*8*4;
      if(wv){
        #pragma unroll 4
        for(int c4=0;c4<16;c4++){
          float4 v = p[c4];
          const float* wq = wp + c4*32;
          #pragma unroll
          for(int k=0;k<KSZ;k++)
            acc[k] += v.x*wq[k*4+0] + v.y*wq[k*4+1] + v.z*wq[k*4+2] + v.w*wq[k*4+3];
        }
      }
    }
  }
  float y[KSZ];
  #pragma unroll
  for(int k=0;k<KSZ;k++){
    float sc = obg[k]*rsqrtf(obv[k]+EPSV);
    float sh = obb[k]-obm[k]*sc;
    y[k] = tanhf(acc[k]*sc+sh);
  }
  float d0 = y[0]+y[1]+y[2], d1=y[1]+y[2], d2=y[2];
  float d4=y[4], d5=y[4]+y[5], d6=y[4]+y[5]+y[6];
  size_t base = ((size_t)b*KSZ)*HPW + rem;
  dyb[base          ] = d0;
  dyb[base +   HPW  ] = d1;
  dyb[base + 2*HPW  ] = d2;
  dyb[base + 3*HPW  ] = 0.f;
  dyb[base + 4*HPW  ] = d4;
  dyb[base + 5*HPW  ] = d5;
  dyb[base + 6*HPW  ] = d6;
}

// ---------------- K5: deform sample + 7x1 conv as bf16 MFMA GEMM ----------------
__global__ __launch_bounds__(256) void k_dsconv(const float* __restrict__ outT,
  const float* __restrict__ dyb, const ushort_t* __restrict__ dsWbf,
  const float* __restrict__ dsb, float* __restrict__ yout)
{
  __shared__ ushort_t S[64*KTOT];      // 57344 B
  __shared__ int sb0[KTOT], sb1[KTOT]; // sample row bases
  __shared__ float swr[KTOT];
  int t = threadIdx.x;
  int wseg = blockIdx.x, h = blockIdx.y, b = blockIdx.z;
  #pragma unroll
  for(int i=0;i<2;i++){
    int e = t + i*256;
    if(e<KTOT){
      int k = e>>6, pz = e&63; int w = wseg*64+pz;
      float dv = dyb[((size_t)(b*KSZ+k)*HH_ + h)*WW + w];
      float r = fminf(fmaxf((float)h + dv, 0.f), 127.f);
      float rf = floorf(r); int r0 = (int)rf; float wr = r - rf; int r1 = min(r0+1,127);
      int c = min(max(w + k - 3,0),127);
      sb0[e] = ((b*HH_ + r0)*WW + c)*CC;
      sb1[e] = ((b*HH_ + r1)*WW + c)*CC;
      swr[e] = wr;
    }
  }
  int wid = t>>6, lane = t&63;
  int arow = lane&15, kgrp = lane>>4;
  bf16x8 aF[14];
  const ushort_t* Wp = dsWbf + (size_t)((wid<<4)+arow)*KTOT + kgrp*8;
  #pragma unroll
  for(int ks=0;ks<14;ks++) aF[ks] = *(const bf16x8*)(Wp + ks*32);
  __syncthreads();
  for(int e=wid; e<KTOT; e+=4){
    int b0 = sb0[e], b1 = sb1[e]; float wr = swr[e];
    float a = outT[b0 + lane];
    float bb = outT[b1 + lane];
    float v = a + wr*(bb-a);
    int pz = e&63; int k = e>>6;
    int idx = pz*KTOT + (k<<6) + lane;      // short index
    S[idx ^ ((pz&7)<<3)] = f2bf(v);         // byte ^= (pz&7)<<4
  }
  __syncthreads();
  f32x4 acc[4];
  #pragma unroll
  for(int nt=0;nt<4;nt++) acc[nt] = (f32x4){0.f,0.f,0.f,0.f};
  #pragma unroll
  for(int nt=0;nt<4;nt++){
    int posb = nt*16 + arow;
    #pragma unroll
    for(int ks=0;ks<14;ks++){
      int off = (posb*(KTOT*2) + ks*64 + kgrp*16) ^ ((posb&7)<<4);
      bf16x8 bF = *(const bf16x8*)((const char*)S + off);
      acc[nt] = __builtin_amdgcn_mfma_f32_16x16x32_bf16(aF[ks], bF, acc[nt], 0,0,0);
    }
  }
  #pragma unroll
  for(int r=0;r<4;r++){
    int co = (wid<<4) + kgrp*4 + r;
    float bias = dsb[co];
    #pragma unroll
    for(int nt=0;nt<4;nt++){
      int wcol = wseg*64 + nt*16 + arow;
      yout[((size_t)(b*CC+co)*HH_ + h)*WW + wcol] = acc[nt][r] + bias;
    }
  }
}

// ---------------- K6: GN partial stats per (b,c) ----------------
__global__ void k_gnstat(const float* __restrict__ y, float* __restrict__ stats){
  int bc = blockIdx.x; int t = threadIdx.x;
  const float4* p = (const float4*)(y + (size_t)bc*HPW);
  float s=0.f, q=0.f;
  for(int i=t;i<HPW/4;i+=256){ float4 v=p[i];
    s += v.x+v.y+v.z+v.w; q += v.x*v.x+v.y*v.y+v.z*v.z+v.w*v.w; }
  for(int o=32;o>0;o>>=1){ s += __shfl_down(s,o); q += __shfl_down(q,o); }
  __shared__ float ls[4], lq[4];
  if((t&63)==0){ ls[t>>6]=s; lq[t>>6]=q; }
  __syncthreads();
  if(t==0){ stats[bc*2] = ls[0]+ls[1]+ls[2]+ls[3]; stats[bc*2+1] = lq[0]+lq[1]+lq[2]+lq[3]; }
}

// ---------------- K6b: finalize group stats ----------------
__global__ void k_gnfin(const float* __restrict__ stats, float* __restrict__ gstat){
  int t = threadIdx.x;
  if(t < BB*16){
    int b=t>>4, gp=t&15;
    float s=0.f,q=0.f;
    for(int i=0;i<4;i++){ int bc = b*CC + gp*4 + i; s += stats[bc*2]; q += stats[bc*2+1]; }
    float inv = 1.0f/(4.0f*HPW);
    float mu = s*inv;
    float var = q*inv - mu*mu;
    gstat[t*2] = mu; gstat[t*2+1] = rsqrtf(var+EPSV);
  }
}

// ---------------- K7: apply GN + affine + relu in place ----------------
__global__ void k_gnapply(float* __restrict__ y, const float* __restrict__ gstat,
  const float* __restrict__ gg, const float* __restrict__ gb){
  int idx = blockIdx.x*256 + threadIdx.x;   // float4 index
  float4* p = (float4*)y;
  int bc = idx >> 12;
  int b = bc>>6, c = bc&63;
  int gi = b*16 + (c>>2);
  float mu = gstat[gi*2], rstd = gstat[gi*2+1];
  float sc = rstd*gg[c], sh = gb[c]-mu*sc;
  float4 v = p[idx];
  v.x = fmaxf(v.x*sc+sh, 0.f);
  v.y = fmaxf(v.y*sc+sh, 0.f);
  v.z = fmaxf(v.z*sc+sh, 0.f);
  v.w = fmaxf(v.w*sc+sh, 0.f);
  p[idx] = v;
}

extern "C" void kernel_launch(void* const* d_in, const int* in_sizes, int n_in,
                              void* d_out, int out_size, void* d_ws, size_t ws_size,
                              hipStream_t stream) {
  const float* x      = (const float*)d_in[0];
  const float* weight = (const float*)d_in[1];
  const float* ratio  = (const float*)d_in[2];
  const float* o1fc   = (const float*)d_in[3];
  const float* o1g    = (const float*)d_in[4];
  const float* o1b    = (const float*)d_in[5];
  const float* o1m    = (const float*)d_in[6];
  const float* o1v    = (const float*)d_in[7];
  const float* o1cw   = (const float*)d_in[8];
  const float* o1cb   = (const float*)d_in[9];
  const float* o1fw   = (const float*)d_in[10];
  const float* o1fb   = (const float*)d_in[11];
  const float* o2fc   = (const float*)d_in[12];
  const float* o2g    = (const float*)d_in[13];
  const float* o2b    = (const float*)d_in[14];
  const float* o2m    = (const float*)d_in[15];
  const float* o2v    = (const float*)d_in[16];
  const float* o2cw   = (const float*)d_in[17];
  const float* o2cb   = (const float*)d_in[18];
  const float* o2fw   = (const float*)d_in[19];
  const float* o2fb   = (const float*)d_in[20];
  const float* spw    = (const float*)d_in[21];
  const float* spb    = (const float*)d_in[22];
  const float* offw   = (const float*)d_in[23];
  const float* offb   = (const float*)d_in[24];
  const float* obg    = (const float*)d_in[25];
  const float* obb    = (const float*)d_in[26];
  const float* obm    = (const float*)d_in[27];
  const float* obv    = (const float*)d_in[28];
  const float* dsw    = (const float*)d_in[29];
  const float* dsb    = (const float*)d_in[30];
  const float* gng    = (const float*)d_in[31];
  const float* gnb    = (const float*)d_in[32];

  float* ws    = (float*)d_ws;
  float* outT  = ws;                 // 4194304
  float* HHb   = ws + 4194304;       // 1048576
  float* dyb   = ws + 5242880;       // 458752
  float* gbuf  = ws + 5701632;       // 256
  float* weff  = ws + 5701888;       // 2304
  ushort_t* dsWbf = (ushort_t*)(ws + 5704192); // 28672 shorts = 14336 floats
  float* offL  = ws + 5718528;       // 4608
  float* stats = ws + 5723136;       // 512
  float* gstat = ws + 5723648;       // 128
  float* attn  = ws + 5723776;       // 1060
  float* outb  = (float*)d_out;      // NCHW scratch: out -> y -> final

  k_prep<<<131,256,0,stream>>>(dsw, offw, dsWbf, offL);
  k_mean<<<256,256,0,stream>>>(x, gbuf);
  k_dwt_hh<<<4096,256,0,stream>>>(x, HHb);
  k_att1<<<1,256,0,stream>>>(gbuf,
    o1fc,o1g,o1b,o1m,o1v,o1cw,o1cb,o1fw,o1fb,
    o2fc,o2g,o2b,o2m,o2v,o2cw,o2cb,o2fw,o2fb,
    spw,spb, attn);
  k_weff<<<256,64,0,stream>>>(weight, attn, ratio, weff);
  k_iwt<<<256,256,0,stream>>>(HHb, x, weff, outb);
  k_transpose<<<512,256,0,stream>>>(outb, outT);
  k_off<<<256,256,0,stream>>>(outT, offL, offb, obg, obb, obm, obv, dyb);
  k_dsconv<<<dim3(2,128,4),256,0,stream>>>(outT, dyb, dsWbf, dsb, outb);
  k_gnstat<<<256,256,0,stream>>>(outb, stats);
  k_gnfin<<<1,64,0,stream>>>(stats, gstat);
  k_gnapply<<<4096,256,0,stream>>>(outb, gstat, gng, gnb);
}